// Round 9
// baseline (159.674 us; speedup 1.0000x reference)
//
#include <hip/hip_runtime.h>
#include <hip/hip_bf16.h>

#define B_  4
#define C_  256
#define C2_ 128
#define N_  4096
#define LOG2E 1.4426950408889634f

typedef unsigned short u16;
typedef __attribute__((ext_vector_type(8))) short bf16x8;   // 8 bf16 in 4 VGPRs
typedef __attribute__((ext_vector_type(4))) float f32x4;
typedef __attribute__((ext_vector_type(16))) float f32x16;  // 32x32 MFMA acc
typedef __attribute__((ext_vector_type(4))) unsigned u32x4;

static __device__ __forceinline__ u16 f2bf(float f) {
    return __builtin_bit_cast(u16, __float2bfloat16(f));
}
static __device__ __forceinline__ float bf2f(u16 u) {
    return __bfloat162float(__builtin_bit_cast(__hip_bfloat16, u));
}
static __device__ __forceinline__ bf16x8 cvt8(const float* p) {
    u16 t[8];
#pragma unroll
    for (int j = 0; j < 8; ++j) t[j] = f2bf(p[j]);
    return *(const bf16x8*)t;
}

// ---------------------------------------------------------------------------
// Kernel 1 (projx): R5-exact proven body. Fused x-transpose + 3-way MFMA
// projection, h-split grid 512, XCD remap xcd=2b+parity, b128 LDS reads.
// LDS: XTs 33792 + Ws 33792 = 67584 B -> 2 blocks/CU.
// ---------------------------------------------------------------------------
#define XW 264

__global__ __launch_bounds__(256, 2) void projx_kernel(
    const float* __restrict__ x,
    const float* __restrict__ wt, const float* __restrict__ wp,
    const float* __restrict__ wg,
    const float* __restrict__ b_theta, const float* __restrict__ b_phi,
    const float* __restrict__ b_g,
    u16* __restrict__ Q, u16* __restrict__ K, u16* __restrict__ V) {
    __shared__ __align__(16) u16 XTs[64][XW];   // 33792 B
    __shared__ __align__(16) u16 Ws[64][XW];    // 33792 B
    u16 (*Vt)[72] = (u16(*)[72])XTs;            // [64][72] overlay after af load

    int p = blockIdx.x;                 // grid 512
    int b = (p & 7) >> 1;               // batch -> XCD pair {2b, 2b+1}
    int j = ((p >> 3) << 1) | (p & 1);  // [0,128)
    int h  = j >> 6;                    // c2-half
    int n0 = (j & 63) * 64;
    int tid = threadIdx.x;
    int wave = tid >> 6, lane = tid & 63, quad = (lane >> 4) & 3, l16 = lane & 15;

    // ---- stage + transpose x tile [256 c][64 n] fp32 -> XTs[n][c] bf16 ----
#pragma unroll
    for (int it = 0; it < 8; ++it) {
        int idx = it * 256 + tid;
        int q = idx & 15, pp = idx >> 4;
        const float* r0 = x + ((size_t)b * C_ + 2 * pp) * N_ + n0 + 4 * q;
        float4 v0 = *(const float4*)r0;
        float4 v1 = *(const float4*)(r0 + N_);
        const float* f0 = (const float*)&v0;
        const float* f1 = (const float*)&v1;
#pragma unroll
        for (int jj = 0; jj < 4; ++jj) {
            unsigned pk = (unsigned)f2bf(f0[jj]) | ((unsigned)f2bf(f1[jj]) << 16);
            *(unsigned*)&XTs[4 * q + jj][2 * pp] = pk;
        }
    }
    __syncthreads();

    bf16x8 af[8];
#pragma unroll
    for (int ks = 0; ks < 8; ++ks)
        af[ks] = *(const bf16x8*)&XTs[wave * 16 + l16][ks * 32 + quad * 8];
    __syncthreads();   // XTs consumed -> Vt may overlay

    const float* wms[3]    = { wt, wp, wg };
    const float* biases[3] = { b_theta, b_phi, b_g };

#pragma unroll
    for (int mat = 0; mat < 3; ++mat) {
        const float* wm = wms[mat];
        const float* bias = biases[mat];
#pragma unroll
        for (int it = 0; it < 8; ++it) {
            int idx = it * 256 + tid;
            int row = idx >> 5, c8 = (idx & 31) * 8;
            const float* src = wm + (size_t)(h * 64 + row) * C_ + c8;
            float w8[8];
            *(float4*)&w8[0] = *(const float4*)src;
            *(float4*)&w8[4] = *(const float4*)(src + 4);
            *(bf16x8*)&Ws[row][c8] = cvt8(w8);
        }
        __syncthreads();

        f32x4 acc[4];
#pragma unroll
        for (int i = 0; i < 4; ++i) acc[i] = (f32x4){0.f, 0.f, 0.f, 0.f};
#pragma unroll
        for (int ct = 0; ct < 4; ++ct)
#pragma unroll
            for (int ks = 0; ks < 8; ++ks) {
                bf16x8 bf = *(const bf16x8*)&Ws[ct * 16 + l16][ks * 32 + quad * 8];
                acc[ct] = __builtin_amdgcn_mfma_f32_16x16x32_bf16(
                    af[ks], bf, acc[ct], 0, 0, 0);
            }

        if (mat < 2) {
            u16* dst = mat == 0 ? Q : K;
            float scl = mat == 0 ? LOG2E : 1.0f;
#pragma unroll
            for (int ct = 0; ct < 4; ++ct) {
                int c2 = h * 64 + ct * 16 + l16;
                float bb = bias[c2];
#pragma unroll
                for (int r = 0; r < 4; ++r) {
                    int n = n0 + wave * 16 + quad * 4 + r;
                    dst[((size_t)b * N_ + n) * C2_ + c2] =
                        f2bf((acc[ct][r] + bb) * scl);
                }
            }
        } else {
#pragma unroll
            for (int ct = 0; ct < 4; ++ct) {
                int c2l = ct * 16 + l16;
                float bb = bias[h * 64 + c2l];
#pragma unroll
                for (int r = 0; r < 4; ++r)
                    Vt[c2l][wave * 16 + quad * 4 + r] = f2bf(acc[ct][r] + bb);
            }
        }
        __syncthreads();
    }

#pragma unroll
    for (int it = 0; it < 2; ++it) {
        int idx = it * 256 + tid;
        int row = idx >> 3, n8 = (idx & 7) * 8;
        *(uint4*)(V + ((size_t)b * C2_ + h * 64 + row) * N_ + n0 + n8) =
            *(const uint4*)&Vt[row][n8];
    }
}

// ---------------------------------------------------------------------------
// Kernel 2: flash attention — R8 proven body (swapped-operand 32x32x16 QK,
// in-register softmax, permuted V staging, 46.5us) with ONE R9 change:
// the epilogue transpose buffer Ob is ALIASED into the Ks+Vs space (dead
// after the loop-final barrier; per-wave disjoint; own-wave RAW needs no
// barrier). LDS 70656 -> 35840 B -> 4 blocks/CU; with VGPR 104 (<=128) that
// doubles resident waves to 4/SIMD, filling the ~73%-busy LDS pipe.
// S=8 (grid 1024) to populate 4 blocks/CU. XCD remap kept.
// ---------------------------------------------------------------------------
__global__ __launch_bounds__(256, 2) void attn_kernel(
    const u16* __restrict__ Q, const u16* __restrict__ K,
    const u16* __restrict__ V, u16* __restrict__ AO,
    u16* __restrict__ Opb, float* __restrict__ lsum, int nsplit) {
    const int BM = 128, BN = 64, D = C2_;
    int p = blockIdx.x;
    int b = (p & 7) >> 1;
    int j = ((p >> 3) << 1) | (p & 1);  // [0, 32*nsplit)
    int s  = j >> 5;
    int m0 = (j & 31) * BM;
    int tid  = threadIdx.x;
    int wave = tid >> 6, lane = tid & 63;
    int l32 = lane & 31, hi8 = (lane >> 5) * 8, hi4 = (lane >> 5) * 4;

    // Flat LDS: Ks [64][136] (17408 B) + Vs [128][72] (18432 B) = 35840 B.
    // Epilogue Ob (4 waves x [32][136] = 34816 B) aliases the same space.
    __shared__ __align__(16) u16 smem[17920];
    u16 (*Ks)[136] = (u16(*)[136])smem;
    u16 (*Vs)[72]  = (u16(*)[72])(smem + 8704);
    u16* obw = smem + wave * 4352;              // per-wave [32][136] overlay

    // Q fragments: row m = l32, k-slice = hi8 + 16c  (B-operand of QK)
    bf16x8 qf[8];
    {
        const u16* qp = Q + ((size_t)b * N_ + m0 + wave * 32 + l32) * D + hi8;
#pragma unroll
        for (int c = 0; c < 8; ++c)
            qf[c] = *(const bf16x8*)(qp + c * 16);
    }

    float l_r = 0.f;
    f32x16 o_acc[4];
#pragma unroll
    for (int i = 0; i < 4; ++i)
#pragma unroll
        for (int r = 0; r < 16; ++r) o_acc[i][r] = 0.f;

    const int tiles = N_ / BN;                 // 64
    const int base = tiles / nsplit, rem = tiles % nsplit;
    const int t0 = s * base + (s < rem ? s : rem);
    const int cnt = base + (s < rem ? 1 : 0);
    const int nt0 = t0 * BN, nt1 = (t0 + cnt) * BN;

    for (int nt = nt0; nt < nt1; nt += BN) {
        // ---- stage K [64 n][128 d] ----
        const u16* kp = K + ((size_t)b * N_ + nt) * D;
#pragma unroll
        for (int it = 0; it < 4; ++it) {
            int idx = it * 256 + tid;
            int row = idx >> 4, col = (idx & 15) * 8;
            *(uint4*)&Ks[row][col] = *(const uint4*)(kp + row * D + col);
        }
        // ---- stage V [128 d][64 n], granules 1<->2 swapped per 16-col ----
#pragma unroll
        for (int it = 0; it < 4; ++it) {
            int idx = it * 256 + tid;
            int row = idx >> 3, col = (idx & 7) * 8;
            uint4 raw = *(const uint4*)(V + ((size_t)b * C2_ + row) * N_ + nt + col);
            int dst = (col & ~15) + ((col & 8) >> 1);
            *(uint2*)&Vs[row][dst]     = make_uint2(raw.x, raw.y);
            *(uint2*)&Vs[row][dst + 8] = make_uint2(raw.z, raw.w);
        }
        __syncthreads();

        // ---- QK^T: two independent 32x32 n-blocks, 8 k-chunks each ----
        f32x16 sc0, sc1;
#pragma unroll
        for (int r = 0; r < 16; ++r) { sc0[r] = 0.f; sc1[r] = 0.f; }
#pragma unroll
        for (int c = 0; c < 8; ++c) {
            bf16x8 kf0 = *(const bf16x8*)&Ks[l32][c * 16 + hi8];
            bf16x8 kf1 = *(const bf16x8*)&Ks[32 + l32][c * 16 + hi8];
            sc0 = __builtin_amdgcn_mfma_f32_32x32x16_bf16(kf0, qf[c], sc0, 0, 0, 0);
            sc1 = __builtin_amdgcn_mfma_f32_32x32x16_bf16(kf1, qf[c], sc1, 0, 0, 0);
        }

        // ---- exp2 + pack in registers; lane's regs ARE its PV B-frags ----
        unsigned w0[8], w1[8];
#pragma unroll
        for (int t = 0; t < 8; ++t) {
            float a0 = __builtin_amdgcn_exp2f(sc0[2 * t]);
            float a1 = __builtin_amdgcn_exp2f(sc0[2 * t + 1]);
            float b0 = __builtin_amdgcn_exp2f(sc1[2 * t]);
            float b1 = __builtin_amdgcn_exp2f(sc1[2 * t + 1]);
            l_r += (a0 + a1) + (b0 + b1);
            w0[t] = (unsigned)f2bf(a0) | ((unsigned)f2bf(a1) << 16);
            w1[t] = (unsigned)f2bf(b0) | ((unsigned)f2bf(b1) << 16);
        }
        bf16x8 pf[4];
        pf[0] = __builtin_bit_cast(bf16x8, (u32x4){w0[0], w0[1], w0[2], w0[3]});
        pf[1] = __builtin_bit_cast(bf16x8, (u32x4){w0[4], w0[5], w0[6], w0[7]});
        pf[2] = __builtin_bit_cast(bf16x8, (u32x4){w1[0], w1[1], w1[2], w1[3]});
        pf[3] = __builtin_bit_cast(bf16x8, (u32x4){w1[4], w1[5], w1[6], w1[7]});

        // ---- PV: 4 k-chunks x 4 d-blocks, V from permuted LDS ----
#pragma unroll
        for (int c = 0; c < 4; ++c)
#pragma unroll
            for (int dblk = 0; dblk < 4; ++dblk) {
                bf16x8 vf = *(const bf16x8*)&Vs[dblk * 32 + l32][c * 16 + hi8];
                o_acc[dblk] = __builtin_amdgcn_mfma_f32_32x32x16_bf16(
                    vf, pf[c], o_acc[dblk], 0, 0, 0);
            }
        __syncthreads();   // Ks/Vs reads complete before next restage (and
                           // before the epilogue Ob overlay after the loop)
    }

    // ---- epilogue: softmax denom + coalesced writeout via LDS transpose ----
    float l_tot = l_r + __shfl_xor(l_r, 32);
    float scale = Opb ? 1.0f : 1.0f / l_tot;

#pragma unroll
    for (int dblk = 0; dblk < 4; ++dblk)
#pragma unroll
        for (int r = 0; r < 16; ++r) {
            int d = dblk * 32 + (r & 3) + 8 * (r >> 2) + hi4;
            obw[l32 * 136 + d] = f2bf(o_acc[dblk][r] * scale);
        }
    // own-wave LDS RAW: no barrier needed (wave-ordered ds ops)

    int mloc = lane >> 1, half = lane & 1;
    if (Opb) {
        size_t row = (size_t)s * (B_ * N_) + (size_t)b * N_ + m0 + wave * 32 + mloc;
#pragma unroll
        for (int k = 0; k < 8; ++k)
            *(uint4*)(Opb + row * C2_ + half * 64 + k * 8) =
                *(const uint4*)&obw[mloc * 136 + half * 64 + k * 8];
        if (lane < 32)
            lsum[(size_t)s * (B_ * N_) + (size_t)b * N_ + m0 + wave * 32 + lane] = l_tot;
    } else {
        size_t row = (size_t)b * N_ + m0 + wave * 32 + mloc;
#pragma unroll
        for (int k = 0; k < 8; ++k)
            *(uint4*)(AO + row * C2_ + half * 64 + k * 8) =
                *(const uint4*)&obw[mloc * 136 + half * 64 + k * 8];
    }
}

// ---------------------------------------------------------------------------
// Kernel 3: outproj — R5-exact (XCD remap + Yt epilogue bounce), generic
// over nsplit (now 8). LDS 35072 -> 4 blocks/CU.
// ---------------------------------------------------------------------------
#define OW 136

__global__ __launch_bounds__(256, 4) void outproj_kernel(
    const float* __restrict__ x, const u16* __restrict__ Opb,
    const float* __restrict__ lsum, const u16* __restrict__ AO,
    const float* __restrict__ w_out, const float* __restrict__ b_out,
    float* __restrict__ y, int nsplit) {
    __shared__ __align__(16) u16 As[64][OW];     // 17408 B
    __shared__ __align__(16) u16 Ws2[64][OW];    // 17408 B
    __shared__ float Ls[64];
    float (*Yt)[68] = (float(*)[68])&As[0][0];   // overlay, 17408 B exactly

    int p = blockIdx.x;
    int b = (p & 7) >> 1;
    int j = ((p >> 3) << 1) | (p & 1);  // [0,256)
    int c0 = (j >> 6) * 64;
    int n0 = (j & 63) * 64;
    int tid = threadIdx.x;
    int wave = tid >> 6, lane = tid & 63, quad = (lane >> 4) & 3, l16 = lane & 15;

#pragma unroll
    for (int it = 0; it < 4; ++it) {
        int idx = it * 256 + tid;
        int row = idx >> 4, c8 = (idx & 15) * 8;
        const float* src = w_out + (size_t)(c0 + row) * C2_ + c8;
        float w8[8];
        *(float4*)&w8[0] = *(const float4*)src;
        *(float4*)&w8[4] = *(const float4*)(src + 4);
        *(bf16x8*)&Ws2[row][c8] = cvt8(w8);
    }

    if (nsplit > 1) {   // grid-uniform branch
        if (tid < 64) {
            float L = 0.f;
            for (int s = 0; s < nsplit; ++s)
                L += lsum[(size_t)s * (B_ * N_) + (size_t)b * N_ + n0 + tid];
            Ls[tid] = 1.f / L;
        }
        __syncthreads();
#pragma unroll
        for (int it = 0; it < 4; ++it) {
            int idx = it * 256 + tid;
            int n = idx >> 4, c8 = (idx & 15) * 8;
            float a[8] = {0.f, 0.f, 0.f, 0.f, 0.f, 0.f, 0.f, 0.f};
            for (int s = 0; s < nsplit; ++s) {
                const u16* op = Opb +
                    ((size_t)s * (B_ * N_) + (size_t)b * N_ + n0 + n) * C2_ + c8;
                uint4 raw = *(const uint4*)op;
                const u16* rp = (const u16*)&raw;
#pragma unroll
                for (int jj = 0; jj < 8; ++jj) a[jj] += bf2f(rp[jj]);
            }
            float inv = Ls[n];
            u16 o[8];
#pragma unroll
            for (int jj = 0; jj < 8; ++jj) o[jj] = f2bf(a[jj] * inv);
            *(uint4*)&As[n][c8] = *(const uint4*)o;
        }
    } else {
#pragma unroll
        for (int it = 0; it < 4; ++it) {
            int idx = it * 256 + tid;
            int n = idx >> 4, c8 = (idx & 15) * 8;
            *(uint4*)&As[n][c8] =
                *(const uint4*)(AO + ((size_t)b * N_ + n0 + n) * C2_ + c8);
        }
    }
    __syncthreads();

    bf16x8 af[4];
#pragma unroll
    for (int kk = 0; kk < 4; ++kk)
        af[kk] = *(const bf16x8*)&Ws2[wave * 16 + l16][kk * 32 + quad * 8];

    f32x4 acc[4];
#pragma unroll
    for (int i = 0; i < 4; ++i) acc[i] = (f32x4){0.f, 0.f, 0.f, 0.f};

#pragma unroll
    for (int nn = 0; nn < 4; ++nn)
#pragma unroll
        for (int kk = 0; kk < 4; ++kk) {
            bf16x8 bf = *(const bf16x8*)&As[nn * 16 + l16][kk * 32 + quad * 8];
            acc[nn] = __builtin_amdgcn_mfma_f32_16x16x32_bf16(af[kk], bf, acc[nn], 0, 0, 0);
        }

    int cw = c0 + wave * 16;
    float bo[4];
#pragma unroll
    for (int r = 0; r < 4; ++r) bo[r] = b_out[cw + quad * 4 + r];

    __syncthreads();   // all waves done reading As -> Yt may overlay
#pragma unroll
    for (int nn = 0; nn < 4; ++nn)
#pragma unroll
        for (int r = 0; r < 4; ++r)
            Yt[wave * 16 + quad * 4 + r][nn * 16 + l16] = acc[nn][r] + bo[r];
    __syncthreads();

    {
        int row = tid >> 2, sg = (tid & 3) * 16;
        const float4* xr = (const float4*)(x + ((size_t)b * C_ + c0 + row) * N_ + n0 + sg);
        float4*       yr = (float4*)(y + ((size_t)b * C_ + c0 + row) * N_ + n0 + sg);
        const float4* tr = (const float4*)&Yt[row][sg];
#pragma unroll
        for (int jj = 0; jj < 4; ++jj) {
            float4 xv = xr[jj];
            float4 tv = tr[jj];
            yr[jj] = make_float4(xv.x + tv.x, xv.y + tv.y,
                                 xv.z + tv.z, xv.w + tv.w);
        }
    }
}

// ---------------------------------------------------------------------------
extern "C" void kernel_launch(void* const* d_in, const int* in_sizes, int n_in,
                              void* d_out, int out_size, void* d_ws, size_t ws_size,
                              hipStream_t stream) {
    const float* x       = (const float*)d_in[0];
    const float* w_theta = (const float*)d_in[1];
    const float* b_theta = (const float*)d_in[2];
    const float* w_phi   = (const float*)d_in[3];
    const float* b_phi   = (const float*)d_in[4];
    const float* w_g     = (const float*)d_in[5];
    const float* b_g     = (const float*)d_in[6];
    const float* w_out   = (const float*)d_in[7];
    const float* b_out   = (const float*)d_in[8];
    float* y = (float*)d_out;

    const size_t SZ = (size_t)B_ * N_ * C2_;        // 2Mi elements
    u16* Q = (u16*)d_ws;
    u16* K = Q + SZ;
    u16* V = K + SZ;
    char* dyn = (char*)(V + SZ);
    size_t fixedB = 3 * SZ * 2;                      // 12 MiB

    size_t perS = SZ * 2 + (size_t)B_ * N_ * 4;      // Opb bf16 + lsum per split

    int S;
    if      (ws_size >= fixedB + 8 * perS) S = 8;    // grid 1024 = 4 blk/CU
    else if (ws_size >= fixedB + 4 * perS) S = 4;
    else if (ws_size >= fixedB + 2 * perS) S = 2;
    else                                   S = 1;

    u16*   AO  = (u16*)dyn;       // used only when S == 1
    u16*   Opb = nullptr;
    float* ls  = nullptr;
    if (S > 1) {
        Opb = (u16*)dyn;          // aliases AO (AO unused when split)
        ls  = (float*)(Opb + (size_t)S * SZ);
    }

    projx_kernel<<<B_ * (N_ / 64) * 2, 256, 0, stream>>>(
        x, w_theta, w_phi, w_g, b_theta, b_phi, b_g, Q, K, V);
    attn_kernel<<<B_ * (N_ / 128) * S, 256, 0, stream>>>(Q, K, V, AO, Opb, ls, S);
    outproj_kernel<<<B_ * (C_ / 64) * (N_ / 64), 256, 0, stream>>>(
        x, Opb, ls, AO, w_out, b_out, y, S);
}

// Round 10
// 156.522 us; speedup vs baseline: 1.0201x; 1.0201x over previous
//
#include <hip/hip_runtime.h>
#include <hip/hip_bf16.h>

#define B_  4
#define C_  256
#define C2_ 128
#define N_  4096
#define LOG2E 1.4426950408889634f

typedef unsigned short u16;
typedef __attribute__((ext_vector_type(8))) short bf16x8;   // 8 bf16 in 4 VGPRs
typedef __attribute__((ext_vector_type(4))) float f32x4;
typedef __attribute__((ext_vector_type(16))) float f32x16;  // 32x32 MFMA acc
typedef __attribute__((ext_vector_type(4))) unsigned u32x4;

static __device__ __forceinline__ u16 f2bf(float f) {
    return __builtin_bit_cast(u16, __float2bfloat16(f));
}
static __device__ __forceinline__ float bf2f(u16 u) {
    return __bfloat162float(__builtin_bit_cast(__hip_bfloat16, u));
}
static __device__ __forceinline__ bf16x8 cvt8(const float* p) {
    u16 t[8];
#pragma unroll
    for (int j = 0; j < 8; ++j) t[j] = f2bf(p[j]);
    return *(const bf16x8*)t;
}

// ---------------------------------------------------------------------------
// Kernel 1 (projx): R5-exact proven body. Fused x-transpose + 3-way MFMA
// projection, h-split grid 512, XCD remap xcd=2b+parity, b128 LDS reads.
// LDS: XTs 33792 + Ws 33792 = 67584 B -> 2 blocks/CU.
// ---------------------------------------------------------------------------
#define XW 264

__global__ __launch_bounds__(256, 2) void projx_kernel(
    const float* __restrict__ x,
    const float* __restrict__ wt, const float* __restrict__ wp,
    const float* __restrict__ wg,
    const float* __restrict__ b_theta, const float* __restrict__ b_phi,
    const float* __restrict__ b_g,
    u16* __restrict__ Q, u16* __restrict__ K, u16* __restrict__ V) {
    __shared__ __align__(16) u16 XTs[64][XW];   // 33792 B
    __shared__ __align__(16) u16 Ws[64][XW];    // 33792 B
    u16 (*Vt)[72] = (u16(*)[72])XTs;            // [64][72] overlay after af load

    int p = blockIdx.x;                 // grid 512
    int b = (p & 7) >> 1;               // batch -> XCD pair {2b, 2b+1}
    int j = ((p >> 3) << 1) | (p & 1);  // [0,128)
    int h  = j >> 6;                    // c2-half
    int n0 = (j & 63) * 64;
    int tid = threadIdx.x;
    int wave = tid >> 6, lane = tid & 63, quad = (lane >> 4) & 3, l16 = lane & 15;

    // ---- stage + transpose x tile [256 c][64 n] fp32 -> XTs[n][c] bf16 ----
#pragma unroll
    for (int it = 0; it < 8; ++it) {
        int idx = it * 256 + tid;
        int q = idx & 15, pp = idx >> 4;
        const float* r0 = x + ((size_t)b * C_ + 2 * pp) * N_ + n0 + 4 * q;
        float4 v0 = *(const float4*)r0;
        float4 v1 = *(const float4*)(r0 + N_);
        const float* f0 = (const float*)&v0;
        const float* f1 = (const float*)&v1;
#pragma unroll
        for (int jj = 0; jj < 4; ++jj) {
            unsigned pk = (unsigned)f2bf(f0[jj]) | ((unsigned)f2bf(f1[jj]) << 16);
            *(unsigned*)&XTs[4 * q + jj][2 * pp] = pk;
        }
    }
    __syncthreads();

    bf16x8 af[8];
#pragma unroll
    for (int ks = 0; ks < 8; ++ks)
        af[ks] = *(const bf16x8*)&XTs[wave * 16 + l16][ks * 32 + quad * 8];
    __syncthreads();   // XTs consumed -> Vt may overlay

    const float* wms[3]    = { wt, wp, wg };
    const float* biases[3] = { b_theta, b_phi, b_g };

#pragma unroll
    for (int mat = 0; mat < 3; ++mat) {
        const float* wm = wms[mat];
        const float* bias = biases[mat];
#pragma unroll
        for (int it = 0; it < 8; ++it) {
            int idx = it * 256 + tid;
            int row = idx >> 5, c8 = (idx & 31) * 8;
            const float* src = wm + (size_t)(h * 64 + row) * C_ + c8;
            float w8[8];
            *(float4*)&w8[0] = *(const float4*)src;
            *(float4*)&w8[4] = *(const float4*)(src + 4);
            *(bf16x8*)&Ws[row][c8] = cvt8(w8);
        }
        __syncthreads();

        f32x4 acc[4];
#pragma unroll
        for (int i = 0; i < 4; ++i) acc[i] = (f32x4){0.f, 0.f, 0.f, 0.f};
#pragma unroll
        for (int ct = 0; ct < 4; ++ct)
#pragma unroll
            for (int ks = 0; ks < 8; ++ks) {
                bf16x8 bf = *(const bf16x8*)&Ws[ct * 16 + l16][ks * 32 + quad * 8];
                acc[ct] = __builtin_amdgcn_mfma_f32_16x16x32_bf16(
                    af[ks], bf, acc[ct], 0, 0, 0);
            }

        if (mat < 2) {
            u16* dst = mat == 0 ? Q : K;
            float scl = mat == 0 ? LOG2E : 1.0f;
#pragma unroll
            for (int ct = 0; ct < 4; ++ct) {
                int c2 = h * 64 + ct * 16 + l16;
                float bb = bias[c2];
#pragma unroll
                for (int r = 0; r < 4; ++r) {
                    int n = n0 + wave * 16 + quad * 4 + r;
                    dst[((size_t)b * N_ + n) * C2_ + c2] =
                        f2bf((acc[ct][r] + bb) * scl);
                }
            }
        } else {
#pragma unroll
            for (int ct = 0; ct < 4; ++ct) {
                int c2l = ct * 16 + l16;
                float bb = bias[h * 64 + c2l];
#pragma unroll
                for (int r = 0; r < 4; ++r)
                    Vt[c2l][wave * 16 + quad * 4 + r] = f2bf(acc[ct][r] + bb);
            }
        }
        __syncthreads();
    }

#pragma unroll
    for (int it = 0; it < 2; ++it) {
        int idx = it * 256 + tid;
        int row = idx >> 3, n8 = (idx & 7) * 8;
        *(uint4*)(V + ((size_t)b * C2_ + h * 64 + row) * N_ + n0 + n8) =
            *(const uint4*)&Vt[row][n8];
    }
}

// ---------------------------------------------------------------------------
// Kernel 2: flash attention — R8 body (swapped-operand 32x32x16 QK,
// in-register softmax, permuted V staging; 46.5us) + R10 change:
// DOUBLE-BUFFERED K/V staging with ONE barrier per tile.
// R9 lesson: true per-wave regs (arch+acc) > 170 -> occupancy pinned at
// 2 waves/SIMD regardless of LDS; so instead of chasing occupancy, use the
// R9-freed LDS for a second K/V buffer (2 x 35840 = 71680 B, 2 blocks/CU).
// Pipeline per tile: issue next-tile global loads (regs) -> QK(cur) ->
// exp2/pack -> commit regs to buf^1 -> PV(cur) -> barrier. Loads hide under
// ~16 MFMA + 32 exp2; prefetch regs live only across QK (branch-free via
// clamped redundant last-tile load -> no R6-style conditional-liveness
// spill). Barriers/tile: 2 -> 1. S=4 restored (S=8 at 2 blk/CU = 2 serial
// passes + doubled overhead, R9's regression).
// ---------------------------------------------------------------------------
__global__ __launch_bounds__(256, 2) void attn_kernel(
    const u16* __restrict__ Q, const u16* __restrict__ K,
    const u16* __restrict__ V, u16* __restrict__ AO,
    u16* __restrict__ Opb, float* __restrict__ lsum, int nsplit) {
    const int BM = 128, BN = 64, D = C2_;
    int p = blockIdx.x;
    int b = (p & 7) >> 1;
    int j = ((p >> 3) << 1) | (p & 1);  // [0, 32*nsplit)
    int s  = j >> 5;
    int m0 = (j & 31) * BM;
    int tid  = threadIdx.x;
    int wave = tid >> 6, lane = tid & 63;
    int l32 = lane & 31, hi8 = (lane >> 5) * 8, hi4 = (lane >> 5) * 4;

    // Two buffers: each {Ks [64][136] 8704 u16 | Vs [128][72] 9216 u16}
    // = 17920 u16 (35840 B); total 71680 B -> 2 blocks/CU.
    __shared__ __align__(16) u16 smem[35840];
    u16* obw = smem + wave * 4352;              // epilogue overlay (buf0 area)

    // Q fragments: row m = l32, k-slice = hi8 + 16c  (B-operand of QK)
    bf16x8 qf[8];
    {
        const u16* qp = Q + ((size_t)b * N_ + m0 + wave * 32 + l32) * D + hi8;
#pragma unroll
        for (int c = 0; c < 8; ++c)
            qf[c] = *(const bf16x8*)(qp + c * 16);
    }

    float l_r = 0.f;
    f32x16 o_acc[4];
#pragma unroll
    for (int i = 0; i < 4; ++i)
#pragma unroll
        for (int r = 0; r < 16; ++r) o_acc[i][r] = 0.f;

    const int tiles = N_ / BN;                 // 64
    const int base = tiles / nsplit, rem = tiles % nsplit;
    const int t0 = s * base + (s < rem ? s : rem);
    const int cnt = base + (s < rem ? 1 : 0);
    const int nt0 = t0 * BN, nt1 = (t0 + cnt) * BN;

    const u16* kbase = K + (size_t)b * N_ * D;
    const u16* vbase = V + (size_t)b * C2_ * N_;

    // per-thread staging indices (fixed across tiles)
    int krow = tid >> 4,  kcol = (tid & 15) * 8;    // +64/iter on tid>>4? no:
    // K items: idx = it*256+tid -> row = idx>>4 (=krow + it*16), col fixed
    int vrow = tid >> 3,  vcol = (tid & 7) * 8;     // V: row = vrow + it*32
    int vdst = (vcol & ~15) + ((vcol & 8) >> 1);    // permuted column

    // ---- prologue: stage tile nt0 into buf0 ----
    {
        uint4 kp4[4], vp4[4];
#pragma unroll
        for (int it = 0; it < 4; ++it)
            kp4[it] = *(const uint4*)(kbase + (size_t)(nt0 + krow + it * 16) * D + kcol);
#pragma unroll
        for (int it = 0; it < 4; ++it)
            vp4[it] = *(const uint4*)(vbase + (size_t)(vrow + it * 32) * N_ + nt0 + vcol);
#pragma unroll
        for (int it = 0; it < 4; ++it)
            *(uint4*)(smem + (krow + it * 16) * 136 + kcol) = kp4[it];
#pragma unroll
        for (int it = 0; it < 4; ++it) {
            uint4 raw = vp4[it];
            u16* vb = smem + 8704 + (vrow + it * 32) * 72;
            *(uint2*)(vb + vdst)     = make_uint2(raw.x, raw.y);
            *(uint2*)(vb + vdst + 8) = make_uint2(raw.z, raw.w);
        }
    }
    __syncthreads();

    int cur = 0;
    for (int i = 0; i < cnt; ++i) {
        int nt  = nt0 + i * BN;
        int ntn = (nt + BN < nt1) ? nt + BN : nt;   // clamped (branch-free)
        u16* Kc = smem + cur * 17920;
        u16* Vc = Kc + 8704;
        u16* Kn = smem + (cur ^ 1) * 17920;
        u16* Vn = Kn + 8704;

        // ---- issue next-tile loads (latency hides under QK + exp2) ----
        uint4 kp4[4], vp4[4];
#pragma unroll
        for (int it = 0; it < 4; ++it)
            kp4[it] = *(const uint4*)(kbase + (size_t)(ntn + krow + it * 16) * D + kcol);
#pragma unroll
        for (int it = 0; it < 4; ++it)
            vp4[it] = *(const uint4*)(vbase + (size_t)(vrow + it * 32) * N_ + ntn + vcol);

        // ---- QK^T: two independent 32x32 n-blocks, 8 k-chunks each ----
        f32x16 sc0, sc1;
#pragma unroll
        for (int r = 0; r < 16; ++r) { sc0[r] = 0.f; sc1[r] = 0.f; }
#pragma unroll
        for (int c = 0; c < 8; ++c) {
            bf16x8 kf0 = *(const bf16x8*)(Kc + l32 * 136 + c * 16 + hi8);
            bf16x8 kf1 = *(const bf16x8*)(Kc + (32 + l32) * 136 + c * 16 + hi8);
            sc0 = __builtin_amdgcn_mfma_f32_32x32x16_bf16(kf0, qf[c], sc0, 0, 0, 0);
            sc1 = __builtin_amdgcn_mfma_f32_32x32x16_bf16(kf1, qf[c], sc1, 0, 0, 0);
        }

        // ---- exp2 + pack in registers ----
        unsigned w0[8], w1[8];
#pragma unroll
        for (int t = 0; t < 8; ++t) {
            float a0 = __builtin_amdgcn_exp2f(sc0[2 * t]);
            float a1 = __builtin_amdgcn_exp2f(sc0[2 * t + 1]);
            float b0 = __builtin_amdgcn_exp2f(sc1[2 * t]);
            float b1 = __builtin_amdgcn_exp2f(sc1[2 * t + 1]);
            l_r += (a0 + a1) + (b0 + b1);
            w0[t] = (unsigned)f2bf(a0) | ((unsigned)f2bf(a1) << 16);
            w1[t] = (unsigned)f2bf(b0) | ((unsigned)f2bf(b1) << 16);
        }
        bf16x8 pf[4];
        pf[0] = __builtin_bit_cast(bf16x8, (u32x4){w0[0], w0[1], w0[2], w0[3]});
        pf[1] = __builtin_bit_cast(bf16x8, (u32x4){w0[4], w0[5], w0[6], w0[7]});
        pf[2] = __builtin_bit_cast(bf16x8, (u32x4){w1[0], w1[1], w1[2], w1[3]});
        pf[3] = __builtin_bit_cast(bf16x8, (u32x4){w1[4], w1[5], w1[6], w1[7]});

        // ---- commit prefetched tile to the other buffer ----
#pragma unroll
        for (int it = 0; it < 4; ++it)
            *(uint4*)(Kn + (krow + it * 16) * 136 + kcol) = kp4[it];
#pragma unroll
        for (int it = 0; it < 4; ++it) {
            uint4 raw = vp4[it];
            u16* vb = Vn + (vrow + it * 32) * 72;
            *(uint2*)(vb + vdst)     = make_uint2(raw.x, raw.y);
            *(uint2*)(vb + vdst + 8) = make_uint2(raw.z, raw.w);
        }

        // ---- PV: 4 k-chunks x 4 d-blocks, V from permuted LDS ----
#pragma unroll
        for (int c = 0; c < 4; ++c)
#pragma unroll
            for (int dblk = 0; dblk < 4; ++dblk) {
                bf16x8 vf = *(const bf16x8*)(Vc + (dblk * 32 + l32) * 72 + c * 16 + hi8);
                o_acc[dblk] = __builtin_amdgcn_mfma_f32_32x32x16_bf16(
                    vf, pf[c], o_acc[dblk], 0, 0, 0);
            }

        __syncthreads();   // one barrier/tile: cur reads done + next staged
        cur ^= 1;
    }

    // ---- epilogue: softmax denom + coalesced writeout via LDS transpose ----
    float l_tot = l_r + __shfl_xor(l_r, 32);
    float scale = Opb ? 1.0f : 1.0f / l_tot;

#pragma unroll
    for (int dblk = 0; dblk < 4; ++dblk)
#pragma unroll
        for (int r = 0; r < 16; ++r) {
            int d = dblk * 32 + (r & 3) + 8 * (r >> 2) + hi4;
            obw[l32 * 136 + d] = f2bf(o_acc[dblk][r] * scale);
        }
    // own-wave LDS RAW: no barrier needed (wave-ordered ds ops)

    int mloc = lane >> 1, half = lane & 1;
    if (Opb) {
        size_t row = (size_t)s * (B_ * N_) + (size_t)b * N_ + m0 + wave * 32 + mloc;
#pragma unroll
        for (int k = 0; k < 8; ++k)
            *(uint4*)(Opb + row * C2_ + half * 64 + k * 8) =
                *(const uint4*)&obw[mloc * 136 + half * 64 + k * 8];
        if (lane < 32)
            lsum[(size_t)s * (B_ * N_) + (size_t)b * N_ + m0 + wave * 32 + lane] = l_tot;
    } else {
        size_t row = (size_t)b * N_ + m0 + wave * 32 + mloc;
#pragma unroll
        for (int k = 0; k < 8; ++k)
            *(uint4*)(AO + row * C2_ + half * 64 + k * 8) =
                *(const uint4*)&obw[mloc * 136 + half * 64 + k * 8];
    }
}

// ---------------------------------------------------------------------------
// Kernel 3: outproj — R5-exact (XCD remap + Yt epilogue bounce), nsplit=4.
// LDS 35072 -> 4 blocks/CU.
// ---------------------------------------------------------------------------
#define OW 136

__global__ __launch_bounds__(256, 4) void outproj_kernel(
    const float* __restrict__ x, const u16* __restrict__ Opb,
    const float* __restrict__ lsum, const u16* __restrict__ AO,
    const float* __restrict__ w_out, const float* __restrict__ b_out,
    float* __restrict__ y, int nsplit) {
    __shared__ __align__(16) u16 As[64][OW];     // 17408 B
    __shared__ __align__(16) u16 Ws2[64][OW];    // 17408 B
    __shared__ float Ls[64];
    float (*Yt)[68] = (float(*)[68])&As[0][0];   // overlay, 17408 B exactly

    int p = blockIdx.x;
    int b = (p & 7) >> 1;
    int j = ((p >> 3) << 1) | (p & 1);  // [0,256)
    int c0 = (j >> 6) * 64;
    int n0 = (j & 63) * 64;
    int tid = threadIdx.x;
    int wave = tid >> 6, lane = tid & 63, quad = (lane >> 4) & 3, l16 = lane & 15;

#pragma unroll
    for (int it = 0; it < 4; ++it) {
        int idx = it * 256 + tid;
        int row = idx >> 4, c8 = (idx & 15) * 8;
        const float* src = w_out + (size_t)(c0 + row) * C2_ + c8;
        float w8[8];
        *(float4*)&w8[0] = *(const float4*)src;
        *(float4*)&w8[4] = *(const float4*)(src + 4);
        *(bf16x8*)&Ws2[row][c8] = cvt8(w8);
    }

    if (nsplit > 1) {   // grid-uniform branch
        if (tid < 64) {
            float L = 0.f;
            for (int s = 0; s < nsplit; ++s)
                L += lsum[(size_t)s * (B_ * N_) + (size_t)b * N_ + n0 + tid];
            Ls[tid] = 1.f / L;
        }
        __syncthreads();
#pragma unroll
        for (int it = 0; it < 4; ++it) {
            int idx = it * 256 + tid;
            int n = idx >> 4, c8 = (idx & 15) * 8;
            float a[8] = {0.f, 0.f, 0.f, 0.f, 0.f, 0.f, 0.f, 0.f};
            for (int s = 0; s < nsplit; ++s) {
                const u16* op = Opb +
                    ((size_t)s * (B_ * N_) + (size_t)b * N_ + n0 + n) * C2_ + c8;
                uint4 raw = *(const uint4*)op;
                const u16* rp = (const u16*)&raw;
#pragma unroll
                for (int jj = 0; jj < 8; ++jj) a[jj] += bf2f(rp[jj]);
            }
            float inv = Ls[n];
            u16 o[8];
#pragma unroll
            for (int jj = 0; jj < 8; ++jj) o[jj] = f2bf(a[jj] * inv);
            *(uint4*)&As[n][c8] = *(const uint4*)o;
        }
    } else {
#pragma unroll
        for (int it = 0; it < 4; ++it) {
            int idx = it * 256 + tid;
            int n = idx >> 4, c8 = (idx & 15) * 8;
            *(uint4*)&As[n][c8] =
                *(const uint4*)(AO + ((size_t)b * N_ + n0 + n) * C2_ + c8);
        }
    }
    __syncthreads();

    bf16x8 af[4];
#pragma unroll
    for (int kk = 0; kk < 4; ++kk)
        af[kk] = *(const bf16x8*)&Ws2[wave * 16 + l16][kk * 32 + quad * 8];

    f32x4 acc[4];
#pragma unroll
    for (int i = 0; i < 4; ++i) acc[i] = (f32x4){0.f, 0.f, 0.f, 0.f};

#pragma unroll
    for (int nn = 0; nn < 4; ++nn)
#pragma unroll
        for (int kk = 0; kk < 4; ++kk) {
            bf16x8 bf = *(const bf16x8*)&As[nn * 16 + l16][kk * 32 + quad * 8];
            acc[nn] = __builtin_amdgcn_mfma_f32_16x16x32_bf16(af[kk], bf, acc[nn], 0, 0, 0);
        }

    int cw = c0 + wave * 16;
    float bo[4];
#pragma unroll
    for (int r = 0; r < 4; ++r) bo[r] = b_out[cw + quad * 4 + r];

    __syncthreads();   // all waves done reading As -> Yt may overlay
#pragma unroll
    for (int nn = 0; nn < 4; ++nn)
#pragma unroll
        for (int r = 0; r < 4; ++r)
            Yt[wave * 16 + quad * 4 + r][nn * 16 + l16] = acc[nn][r] + bo[r];
    __syncthreads();

    {
        int row = tid >> 2, sg = (tid & 3) * 16;
        const float4* xr = (const float4*)(x + ((size_t)b * C_ + c0 + row) * N_ + n0 + sg);
        float4*       yr = (float4*)(y + ((size_t)b * C_ + c0 + row) * N_ + n0 + sg);
        const float4* tr = (const float4*)&Yt[row][sg];
#pragma unroll
        for (int jj = 0; jj < 4; ++jj) {
            float4 xv = xr[jj];
            float4 tv = tr[jj];
            yr[jj] = make_float4(xv.x + tv.x, xv.y + tv.y,
                                 xv.z + tv.z, xv.w + tv.w);
        }
    }
}

// ---------------------------------------------------------------------------
extern "C" void kernel_launch(void* const* d_in, const int* in_sizes, int n_in,
                              void* d_out, int out_size, void* d_ws, size_t ws_size,
                              hipStream_t stream) {
    const float* x       = (const float*)d_in[0];
    const float* w_theta = (const float*)d_in[1];
    const float* b_theta = (const float*)d_in[2];
    const float* w_phi   = (const float*)d_in[3];
    const float* b_phi   = (const float*)d_in[4];
    const float* w_g     = (const float*)d_in[5];
    const float* b_g     = (const float*)d_in[6];
    const float* w_out   = (const float*)d_in[7];
    const float* b_out   = (const float*)d_in[8];
    float* y = (float*)d_out;

    const size_t SZ = (size_t)B_ * N_ * C2_;        // 2Mi elements
    u16* Q = (u16*)d_ws;
    u16* K = Q + SZ;
    u16* V = K + SZ;
    char* dyn = (char*)(V + SZ);
    size_t fixedB = 3 * SZ * 2;                      // 12 MiB

    size_t perS = SZ * 2 + (size_t)B_ * N_ * 4;      // Opb bf16 + lsum per split

    int S;
    if      (ws_size >= fixedB + 4 * perS) S = 4;    // proven best split
    else if (ws_size >= fixedB + 2 * perS) S = 2;
    else                                   S = 1;

    u16*   AO  = (u16*)dyn;       // used only when S == 1
    u16*   Opb = nullptr;
    float* ls  = nullptr;
    if (S > 1) {
        Opb = (u16*)dyn;          // aliases AO (AO unused when split)
        ls  = (float*)(Opb + (size_t)S * SZ);
    }

    projx_kernel<<<B_ * (N_ / 64) * 2, 256, 0, stream>>>(
        x, w_theta, w_phi, w_g, b_theta, b_phi, b_g, Q, K, V);
    attn_kernel<<<B_ * (N_ / 128) * S, 256, 0, stream>>>(Q, K, V, AO, Opb, ls, S);
    outproj_kernel<<<B_ * (C_ / 64) * (N_ / 64), 256, 0, stream>>>(
        x, Opb, ls, AO, w_out, b_out, y, S);
}

// Round 11
// 147.705 us; speedup vs baseline: 1.0810x; 1.0597x over previous
//
#include <hip/hip_runtime.h>
#include <hip/hip_bf16.h>

#define B_  4
#define C_  256
#define C2_ 128
#define N_  4096
#define LOG2E 1.4426950408889634f

typedef unsigned short u16;
typedef __attribute__((ext_vector_type(8))) short bf16x8;   // 8 bf16 in 4 VGPRs
typedef __attribute__((ext_vector_type(4))) float f32x4;
typedef __attribute__((ext_vector_type(16))) float f32x16;  // 32x32 MFMA acc
typedef __attribute__((ext_vector_type(4))) unsigned u32x4;

static __device__ __forceinline__ u16 f2bf(float f) {
    return __builtin_bit_cast(u16, __float2bfloat16(f));
}
static __device__ __forceinline__ float bf2f(u16 u) {
    return __bfloat162float(__builtin_bit_cast(__hip_bfloat16, u));
}
static __device__ __forceinline__ bf16x8 cvt8(const float* p) {
    u16 t[8];
#pragma unroll
    for (int j = 0; j < 8; ++j) t[j] = f2bf(p[j]);
    return *(const bf16x8*)t;
}

// ---------------------------------------------------------------------------
// Kernel 1 (projx): R5 body + R11 coalesced Q/K epilogue.
// The old Q/K store was 16 scalar u16 globals per thread per mat (fragment
// layout: lane values 16 c2 apart -> unvectorizable per-lane). Now all three
// mats bounce results through the dead Vt overlay and issue 2 coalesced
// uint4 stores per thread per mat. Barrier count unchanged (loop-end barrier
// moved before the coop store). h-split grid 512, XCD remap, b128 LDS reads.
// LDS: XTs 33792 + Ws 33792 = 67584 B -> 2 blocks/CU.
// ---------------------------------------------------------------------------
#define XW 264

__global__ __launch_bounds__(256, 2) void projx_kernel(
    const float* __restrict__ x,
    const float* __restrict__ wt, const float* __restrict__ wp,
    const float* __restrict__ wg,
    const float* __restrict__ b_theta, const float* __restrict__ b_phi,
    const float* __restrict__ b_g,
    u16* __restrict__ Q, u16* __restrict__ K, u16* __restrict__ V) {
    __shared__ __align__(16) u16 XTs[64][XW];   // 33792 B
    __shared__ __align__(16) u16 Ws[64][XW];    // 33792 B
    u16 (*Vt)[72] = (u16(*)[72])XTs;            // [64][72] overlay after af load

    int p = blockIdx.x;                 // grid 512
    int b = (p & 7) >> 1;               // batch -> XCD pair {2b, 2b+1}
    int j = ((p >> 3) << 1) | (p & 1);  // [0,128)
    int h  = j >> 6;                    // c2-half
    int n0 = (j & 63) * 64;
    int tid = threadIdx.x;
    int wave = tid >> 6, lane = tid & 63, quad = (lane >> 4) & 3, l16 = lane & 15;

    // ---- stage + transpose x tile [256 c][64 n] fp32 -> XTs[n][c] bf16 ----
#pragma unroll
    for (int it = 0; it < 8; ++it) {
        int idx = it * 256 + tid;
        int q = idx & 15, pp = idx >> 4;
        const float* r0 = x + ((size_t)b * C_ + 2 * pp) * N_ + n0 + 4 * q;
        float4 v0 = *(const float4*)r0;
        float4 v1 = *(const float4*)(r0 + N_);
        const float* f0 = (const float*)&v0;
        const float* f1 = (const float*)&v1;
#pragma unroll
        for (int jj = 0; jj < 4; ++jj) {
            unsigned pk = (unsigned)f2bf(f0[jj]) | ((unsigned)f2bf(f1[jj]) << 16);
            *(unsigned*)&XTs[4 * q + jj][2 * pp] = pk;
        }
    }
    __syncthreads();

    bf16x8 af[8];
#pragma unroll
    for (int ks = 0; ks < 8; ++ks)
        af[ks] = *(const bf16x8*)&XTs[wave * 16 + l16][ks * 32 + quad * 8];
    __syncthreads();   // XTs consumed -> Vt may overlay

    const float* wms[3]    = { wt, wp, wg };
    const float* biases[3] = { b_theta, b_phi, b_g };

#pragma unroll
    for (int mat = 0; mat < 3; ++mat) {
        const float* wm = wms[mat];
        const float* bias = biases[mat];
        // ---- stage this block's weight half [64 c2][256 c] fp32 -> bf16 ----
#pragma unroll
        for (int it = 0; it < 8; ++it) {
            int idx = it * 256 + tid;
            int row = idx >> 5, c8 = (idx & 31) * 8;
            const float* src = wm + (size_t)(h * 64 + row) * C_ + c8;
            float w8[8];
            *(float4*)&w8[0] = *(const float4*)src;
            *(float4*)&w8[4] = *(const float4*)(src + 4);
            *(bf16x8*)&Ws[row][c8] = cvt8(w8);
        }
        __syncthreads();   // Ws ready; also orders prev mat's Vt coop reads
                           // before this mat's Vt writes (below)

        f32x4 acc[4];
#pragma unroll
        for (int i = 0; i < 4; ++i) acc[i] = (f32x4){0.f, 0.f, 0.f, 0.f};
#pragma unroll
        for (int ct = 0; ct < 4; ++ct)
#pragma unroll
            for (int ks = 0; ks < 8; ++ks) {
                bf16x8 bf = *(const bf16x8*)&Ws[ct * 16 + l16][ks * 32 + quad * 8];
                acc[ct] = __builtin_amdgcn_mfma_f32_16x16x32_bf16(
                    af[ks], bf, acc[ct], 0, 0, 0);
            }

        if (mat < 2) {
            float scl = mat == 0 ? LOG2E : 1.0f;
            // Vt as [n_local][c2_local]
#pragma unroll
            for (int ct = 0; ct < 4; ++ct) {
                int c2l = ct * 16 + l16;
                float bb = bias[h * 64 + c2l];
#pragma unroll
                for (int r = 0; r < 4; ++r)
                    Vt[wave * 16 + quad * 4 + r][c2l] =
                        f2bf((acc[ct][r] + bb) * scl);
            }
            __syncthreads();
            u16* dst = mat == 0 ? Q : K;
#pragma unroll
            for (int it = 0; it < 2; ++it) {
                int idx = it * 256 + tid;
                int row = idx >> 3, c8 = (idx & 7) * 8;   // 64 rows x 8 chunks
                *(uint4*)(dst + ((size_t)b * N_ + n0 + row) * C2_ + h * 64 + c8) =
                    *(const uint4*)&Vt[row][c8];
            }
        } else {
            // Vt as [c2_local][n_local] (V is [b][c2][n])
#pragma unroll
            for (int ct = 0; ct < 4; ++ct) {
                int c2l = ct * 16 + l16;
                float bb = bias[h * 64 + c2l];
#pragma unroll
                for (int r = 0; r < 4; ++r)
                    Vt[c2l][wave * 16 + quad * 4 + r] = f2bf(acc[ct][r] + bb);
            }
            __syncthreads();
#pragma unroll
            for (int it = 0; it < 2; ++it) {
                int idx = it * 256 + tid;
                int row = idx >> 3, n8 = (idx & 7) * 8;   // 64 rows x 8 chunks
                *(uint4*)(V + ((size_t)b * C2_ + h * 64 + row) * N_ + n0 + n8) =
                    *(const uint4*)&Vt[row][n8];
            }
        }
        // next mat's post-stage barrier protects Vt reuse
    }
}

// ---------------------------------------------------------------------------
// Kernel 2: flash attention — R8-EXACT proven body (46.5 µs): swapped-operand
// 32x32x16 QK (scores [n][m], m = lane&31), in-register softmax (P never
// touches LDS), permuted V staging, 2 barriers/tile, separate Ob epilogue
// buffer, S=4, XCD remap. R9 (occupancy via LDS) refuted: true per-wave regs
// (arch+acc) > 170 pin 2 waves/SIMD. R10 (dbuf, 1 barrier) refuted: commit
// writes inside the compute window contend on the dominant LDS pipe.
// LDS: Ks 17408 + Vs 18432 + Ob 34816 = 70656 B -> 2 blocks/CU.
// ---------------------------------------------------------------------------
__global__ __launch_bounds__(256, 2) void attn_kernel(
    const u16* __restrict__ Q, const u16* __restrict__ K,
    const u16* __restrict__ V, u16* __restrict__ AO,
    u16* __restrict__ Opb, float* __restrict__ lsum, int nsplit) {
    const int BM = 128, BN = 64, D = C2_;
    int p = blockIdx.x;
    int b = (p & 7) >> 1;
    int j = ((p >> 3) << 1) | (p & 1);  // [0, 32*nsplit)
    int s  = j >> 5;
    int m0 = (j & 31) * BM;
    int tid  = threadIdx.x;
    int wave = tid >> 6, lane = tid & 63;
    int l32 = lane & 31, hi8 = (lane >> 5) * 8, hi4 = (lane >> 5) * 4;

    __shared__ __align__(16) u16 Ks[64][136];      // 17408 B
    __shared__ __align__(16) u16 Vs[128][72];      // 18432 B (col-permuted)
    __shared__ __align__(16) u16 Ob[4][32][136];   // 34816 B (epilogue xpose)

    // Q fragments: row m = l32, k-slice = hi8 + 16c  (B-operand of QK)
    bf16x8 qf[8];
    {
        const u16* qp = Q + ((size_t)b * N_ + m0 + wave * 32 + l32) * D + hi8;
#pragma unroll
        for (int c = 0; c < 8; ++c)
            qf[c] = *(const bf16x8*)(qp + c * 16);
    }

    float l_r = 0.f;
    f32x16 o_acc[4];
#pragma unroll
    for (int i = 0; i < 4; ++i)
#pragma unroll
        for (int r = 0; r < 16; ++r) o_acc[i][r] = 0.f;

    const int tiles = N_ / BN;                 // 64
    const int base = tiles / nsplit, rem = tiles % nsplit;
    const int t0 = s * base + (s < rem ? s : rem);
    const int cnt = base + (s < rem ? 1 : 0);
    const int nt0 = t0 * BN, nt1 = (t0 + cnt) * BN;

    for (int nt = nt0; nt < nt1; nt += BN) {
        // ---- stage K [64 n][128 d] ----
        const u16* kp = K + ((size_t)b * N_ + nt) * D;
#pragma unroll
        for (int it = 0; it < 4; ++it) {
            int idx = it * 256 + tid;
            int row = idx >> 4, col = (idx & 15) * 8;
            *(uint4*)&Ks[row][col] = *(const uint4*)(kp + row * D + col);
        }
        // ---- stage V [128 d][64 n], granules 1<->2 swapped per 16-col ----
#pragma unroll
        for (int it = 0; it < 4; ++it) {
            int idx = it * 256 + tid;
            int row = idx >> 3, col = (idx & 7) * 8;
            uint4 raw = *(const uint4*)(V + ((size_t)b * C2_ + row) * N_ + nt + col);
            int dst = (col & ~15) + ((col & 8) >> 1);
            *(uint2*)&Vs[row][dst]     = make_uint2(raw.x, raw.y);
            *(uint2*)&Vs[row][dst + 8] = make_uint2(raw.z, raw.w);
        }
        __syncthreads();

        // ---- QK^T: two independent 32x32 n-blocks, 8 k-chunks each ----
        f32x16 sc0, sc1;
#pragma unroll
        for (int r = 0; r < 16; ++r) { sc0[r] = 0.f; sc1[r] = 0.f; }
#pragma unroll
        for (int c = 0; c < 8; ++c) {
            bf16x8 kf0 = *(const bf16x8*)&Ks[l32][c * 16 + hi8];
            bf16x8 kf1 = *(const bf16x8*)&Ks[32 + l32][c * 16 + hi8];
            sc0 = __builtin_amdgcn_mfma_f32_32x32x16_bf16(kf0, qf[c], sc0, 0, 0, 0);
            sc1 = __builtin_amdgcn_mfma_f32_32x32x16_bf16(kf1, qf[c], sc1, 0, 0, 0);
        }

        // ---- exp2 + pack in registers; lane's regs ARE its PV B-frags ----
        unsigned w0[8], w1[8];
#pragma unroll
        for (int t = 0; t < 8; ++t) {
            float a0 = __builtin_amdgcn_exp2f(sc0[2 * t]);
            float a1 = __builtin_amdgcn_exp2f(sc0[2 * t + 1]);
            float b0 = __builtin_amdgcn_exp2f(sc1[2 * t]);
            float b1 = __builtin_amdgcn_exp2f(sc1[2 * t + 1]);
            l_r += (a0 + a1) + (b0 + b1);
            w0[t] = (unsigned)f2bf(a0) | ((unsigned)f2bf(a1) << 16);
            w1[t] = (unsigned)f2bf(b0) | ((unsigned)f2bf(b1) << 16);
        }
        bf16x8 pf[4];
        pf[0] = __builtin_bit_cast(bf16x8, (u32x4){w0[0], w0[1], w0[2], w0[3]});
        pf[1] = __builtin_bit_cast(bf16x8, (u32x4){w0[4], w0[5], w0[6], w0[7]});
        pf[2] = __builtin_bit_cast(bf16x8, (u32x4){w1[0], w1[1], w1[2], w1[3]});
        pf[3] = __builtin_bit_cast(bf16x8, (u32x4){w1[4], w1[5], w1[6], w1[7]});

        // ---- PV: 4 k-chunks x 4 d-blocks, V from permuted LDS ----
#pragma unroll
        for (int c = 0; c < 4; ++c)
#pragma unroll
            for (int dblk = 0; dblk < 4; ++dblk) {
                bf16x8 vf = *(const bf16x8*)&Vs[dblk * 32 + l32][c * 16 + hi8];
                o_acc[dblk] = __builtin_amdgcn_mfma_f32_32x32x16_bf16(
                    vf, pf[c], o_acc[dblk], 0, 0, 0);
            }
        __syncthreads();
    }

    // ---- epilogue: softmax denom + coalesced writeout via LDS transpose ----
    float l_tot = l_r + __shfl_xor(l_r, 32);
    float scale = Opb ? 1.0f : 1.0f / l_tot;

#pragma unroll
    for (int dblk = 0; dblk < 4; ++dblk)
#pragma unroll
        for (int r = 0; r < 16; ++r) {
            int d = dblk * 32 + (r & 3) + 8 * (r >> 2) + hi4;
            Ob[wave][l32][d] = f2bf(o_acc[dblk][r] * scale);
        }
    // own-wave LDS RAW: no barrier needed (wave-ordered ds ops)

    int mloc = lane >> 1, half = lane & 1;
    if (Opb) {
        size_t row = (size_t)s * (B_ * N_) + (size_t)b * N_ + m0 + wave * 32 + mloc;
#pragma unroll
        for (int k = 0; k < 8; ++k)
            *(uint4*)(Opb + row * C2_ + half * 64 + k * 8) =
                *(const uint4*)&Ob[wave][mloc][half * 64 + k * 8];
        if (lane < 32)
            lsum[(size_t)s * (B_ * N_) + (size_t)b * N_ + m0 + wave * 32 + lane] = l_tot;
    } else {
        size_t row = (size_t)b * N_ + m0 + wave * 32 + mloc;
#pragma unroll
        for (int k = 0; k < 8; ++k)
            *(uint4*)(AO + row * C2_ + half * 64 + k * 8) =
                *(const uint4*)&Ob[wave][mloc][half * 64 + k * 8];
    }
}

// ---------------------------------------------------------------------------
// Kernel 3: outproj — R5-exact (XCD remap + Yt epilogue bounce), nsplit=4.
// LDS 35072 -> 4 blocks/CU.
// ---------------------------------------------------------------------------
#define OW 136

__global__ __launch_bounds__(256, 4) void outproj_kernel(
    const float* __restrict__ x, const u16* __restrict__ Opb,
    const float* __restrict__ lsum, const u16* __restrict__ AO,
    const float* __restrict__ w_out, const float* __restrict__ b_out,
    float* __restrict__ y, int nsplit) {
    __shared__ __align__(16) u16 As[64][OW];     // 17408 B
    __shared__ __align__(16) u16 Ws2[64][OW];    // 17408 B
    __shared__ float Ls[64];
    float (*Yt)[68] = (float(*)[68])&As[0][0];   // overlay, 17408 B exactly

    int p = blockIdx.x;
    int b = (p & 7) >> 1;
    int j = ((p >> 3) << 1) | (p & 1);  // [0,256)
    int c0 = (j >> 6) * 64;
    int n0 = (j & 63) * 64;
    int tid = threadIdx.x;
    int wave = tid >> 6, lane = tid & 63, quad = (lane >> 4) & 3, l16 = lane & 15;

#pragma unroll
    for (int it = 0; it < 4; ++it) {
        int idx = it * 256 + tid;
        int row = idx >> 4, c8 = (idx & 15) * 8;
        const float* src = w_out + (size_t)(c0 + row) * C2_ + c8;
        float w8[8];
        *(float4*)&w8[0] = *(const float4*)src;
        *(float4*)&w8[4] = *(const float4*)(src + 4);
        *(bf16x8*)&Ws2[row][c8] = cvt8(w8);
    }

    if (nsplit > 1) {   // grid-uniform branch
        if (tid < 64) {
            float L = 0.f;
            for (int s = 0; s < nsplit; ++s)
                L += lsum[(size_t)s * (B_ * N_) + (size_t)b * N_ + n0 + tid];
            Ls[tid] = 1.f / L;
        }
        __syncthreads();
#pragma unroll
        for (int it = 0; it < 4; ++it) {
            int idx = it * 256 + tid;
            int n = idx >> 4, c8 = (idx & 15) * 8;
            float a[8] = {0.f, 0.f, 0.f, 0.f, 0.f, 0.f, 0.f, 0.f};
            for (int s = 0; s < nsplit; ++s) {
                const u16* op = Opb +
                    ((size_t)s * (B_ * N_) + (size_t)b * N_ + n0 + n) * C2_ + c8;
                uint4 raw = *(const uint4*)op;
                const u16* rp = (const u16*)&raw;
#pragma unroll
                for (int jj = 0; jj < 8; ++jj) a[jj] += bf2f(rp[jj]);
            }
            float inv = Ls[n];
            u16 o[8];
#pragma unroll
            for (int jj = 0; jj < 8; ++jj) o[jj] = f2bf(a[jj] * inv);
            *(uint4*)&As[n][c8] = *(const uint4*)o;
        }
    } else {
#pragma unroll
        for (int it = 0; it < 4; ++it) {
            int idx = it * 256 + tid;
            int n = idx >> 4, c8 = (idx & 15) * 8;
            *(uint4*)&As[n][c8] =
                *(const uint4*)(AO + ((size_t)b * N_ + n0 + n) * C2_ + c8);
        }
    }
    __syncthreads();

    bf16x8 af[4];
#pragma unroll
    for (int kk = 0; kk < 4; ++kk)
        af[kk] = *(const bf16x8*)&Ws2[wave * 16 + l16][kk * 32 + quad * 8];

    f32x4 acc[4];
#pragma unroll
    for (int i = 0; i < 4; ++i) acc[i] = (f32x4){0.f, 0.f, 0.f, 0.f};

#pragma unroll
    for (int nn = 0; nn < 4; ++nn)
#pragma unroll
        for (int kk = 0; kk < 4; ++kk) {
            bf16x8 bf = *(const bf16x8*)&As[nn * 16 + l16][kk * 32 + quad * 8];
            acc[nn] = __builtin_amdgcn_mfma_f32_16x16x32_bf16(af[kk], bf, acc[nn], 0, 0, 0);
        }

    int cw = c0 + wave * 16;
    float bo[4];
#pragma unroll
    for (int r = 0; r < 4; ++r) bo[r] = b_out[cw + quad * 4 + r];

    __syncthreads();   // all waves done reading As -> Yt may overlay
#pragma unroll
    for (int nn = 0; nn < 4; ++nn)
#pragma unroll
        for (int r = 0; r < 4; ++r)
            Yt[wave * 16 + quad * 4 + r][nn * 16 + l16] = acc[nn][r] + bo[r];
    __syncthreads();

    {
        int row = tid >> 2, sg = (tid & 3) * 16;
        const float4* xr = (const float4*)(x + ((size_t)b * C_ + c0 + row) * N_ + n0 + sg);
        float4*       yr = (float4*)(y + ((size_t)b * C_ + c0 + row) * N_ + n0 + sg);
        const float4* tr = (const float4*)&Yt[row][sg];
#pragma unroll
        for (int jj = 0; jj < 4; ++jj) {
            float4 xv = xr[jj];
            float4 tv = tr[jj];
            yr[jj] = make_float4(xv.x + tv.x, xv.y + tv.y,
                                 xv.z + tv.z, xv.w + tv.w);
        }
    }
}

// ---------------------------------------------------------------------------
extern "C" void kernel_launch(void* const* d_in, const int* in_sizes, int n_in,
                              void* d_out, int out_size, void* d_ws, size_t ws_size,
                              hipStream_t stream) {
    const float* x       = (const float*)d_in[0];
    const float* w_theta = (const float*)d_in[1];
    const float* b_theta = (const float*)d_in[2];
    const float* w_phi   = (const float*)d_in[3];
    const float* b_phi   = (const float*)d_in[4];
    const float* w_g     = (const float*)d_in[5];
    const float* b_g     = (const float*)d_in[6];
    const float* w_out   = (const float*)d_in[7];
    const float* b_out   = (const float*)d_in[8];
    float* y = (float*)d_out;

    const size_t SZ = (size_t)B_ * N_ * C2_;        // 2Mi elements
    u16* Q = (u16*)d_ws;
    u16* K = Q + SZ;
    u16* V = K + SZ;
    char* dyn = (char*)(V + SZ);
    size_t fixedB = 3 * SZ * 2;                      // 12 MiB

    size_t perS = SZ * 2 + (size_t)B_ * N_ * 4;      // Opb bf16 + lsum per split

    int S;
    if      (ws_size >= fixedB + 4 * perS) S = 4;    // proven best split
    else if (ws_size >= fixedB + 2 * perS) S = 2;
    else                                   S = 1;

    u16*   AO  = (u16*)dyn;       // used only when S == 1
    u16*   Opb = nullptr;
    float* ls  = nullptr;
    if (S > 1) {
        Opb = (u16*)dyn;          // aliases AO (AO unused when split)
        ls  = (float*)(Opb + (size_t)S * SZ);
    }

    projx_kernel<<<B_ * (N_ / 64) * 2, 256, 0, stream>>>(
        x, w_theta, w_phi, w_g, b_theta, b_phi, b_g, Q, K, V);
    attn_kernel<<<B_ * (N_ / 128) * S, 256, 0, stream>>>(Q, K, V, AO, Opb, ls, S);
    outproj_kernel<<<B_ * (C_ / 64) * (N_ / 64), 256, 0, stream>>>(
        x, Opb, ls, AO, w_out, b_out, y, S);
}